// Round 10
// baseline (272.456 us; speedup 1.0000x reference)
//
#include <hip/hip_runtime.h>
#include <stdint.h>

typedef __attribute__((ext_vector_type(8))) short short8;
typedef __attribute__((ext_vector_type(4))) float f32x4;
typedef unsigned int u32;
typedef unsigned short u16;

#define T_TOK 2048
#define DMODEL 768
#define DFF 2048
#define NEXP 8

#define BKP 40      // (fallback path) padded LDS row stride
#define WSTR 20     // (fallback wpack) uint stride per n-column

// meta ints: [0..7]=cnt [8..15]=cur [16..24]=off
#define M_CNT 0
#define M_CUR 8
#define M_OFF 16

// compact grids: worst-case tile counts (sum rows = 4096)
#define G1_GRID 640   // sum ceil(rows_e/128)*16 <= (32+8)*16 = 640 ; 80/XCD
#define G1_PERX 80
#define G2_GRID 432   // sum ceil(rows_e/64)*6 <= (64+8)*6 = 432 ; 54/XCD
#define G2_PERX 54

// k_prep mega-grid: BARRIER-FREE per-wave wtrans (2 tiles/wave) || router || zero
#define PREP_WT 1152                // 1152 blocks x 4 waves x 2 tiles = 9216 tiles
#define PREP_RT (PREP_WT + 512)     // router blocks
#define PREP_GRID (PREP_RT + 384)   // zero blocks: 384*256*64B = 6291456B = out

__device__ __forceinline__ float b2f(u16 u) {
  union { u32 i; float f; } v; v.i = ((u32)u) << 16; return v.f;
}
__device__ __forceinline__ u16 f2b(float f) {
  union { float f; u32 i; } v; v.f = f;
  return (u16)((v.i + 0x7fffu + ((v.i >> 16) & 1u)) >> 16);
}
__device__ __forceinline__ u32 pack2(float lo, float hi) {
  return (u32)f2b(lo) | ((u32)f2b(hi) << 16);
}
__device__ __forceinline__ uint4 cvt8(float4 a, float4 b) {
  uint4 r; r.x = pack2(a.x, a.y); r.y = pack2(a.z, a.w);
  r.z = pack2(b.x, b.y); r.w = pack2(b.z, b.w); return r;
}
// async global->LDS, 16B per lane; LDS dst = wave-uniform base + lane*16
__device__ __forceinline__ void gl16(const u16* g, u16* l) {
  __builtin_amdgcn_global_load_lds((const __attribute__((address_space(1))) void*)g,
                                   (__attribute__((address_space(3))) void*)l, 16, 0, 0);
}

// ---------------- mega prep: wtrans x3 (barrier-free)  ||  router  ||  zero ----
// wtrans: each WAVE owns a 32x128 fp32 tile in its private LDS quadrant.
// No __syncthreads anywhere -> no vmcnt drains -> tile s+1 loads pipeline
// freely under tile s transpose; 8 independent wave streams per CU.
__global__ __launch_bounds__(256) void k_prep(
    const float* __restrict__ wg, const float* __restrict__ wu, const float* __restrict__ wd,
    const float* __restrict__ x, const float* __restrict__ gw,
    u16* __restrict__ WgB, u16* __restrict__ WuB, u16* __restrict__ WdB,
    int* __restrict__ t2e, float* __restrict__ t2w, u16* __restrict__ xb,
    float* __restrict__ out) {
  __shared__ float TT[4 * 4352];   // 4 waves x [32][136] fp32 (17.4KB each)
  int bid = blockIdx.x;
  int tid = threadIdx.x;
  if (bid < PREP_WT) {
    int lane = tid & 63, w = tid >> 6;
    float* Tw = &TT[w * 4352];
    int tl0 = bid * 8 + w * 2;
#pragma unroll 1
    for (int s = 0; s < 2; ++s) {
      int tl = tl0 + s;
      const float* in; u16* outw; int K, N, t;
      if (tl < 3072) { in = wg; outw = WgB; K = 768; N = 2048; t = tl; }
      else if (tl < 6144) { in = wu; outw = WuB; K = 768; N = 2048; t = tl - 3072; }
      else { in = wd; outw = WdB; K = 2048; N = 768; t = tl - 6144; }
      int e, nx, ky;
      if (K == 768) {                                    // t < 3072: panel=t/24
        int panel = (int)(((unsigned)t * 43691u) >> 20);
        ky = t - panel * 24; e = panel >> 4; nx = panel & 15;
      } else {                                           // panel = t/64, e = panel/6
        int panel = t >> 6; ky = t & 63;
        e = (int)(((unsigned)panel * 43691u) >> 18);
        nx = panel - e * 6;
      }
      const float* src = in + (size_t)e * K * N + (size_t)(ky * 32 + (lane >> 5)) * N
                       + nx * 128 + ((lane & 31) << 2);
      float4 v[16];
#pragma unroll
      for (int j = 0; j < 16; ++j) v[j] = *(const float4*)(src + (size_t)(2 * j) * N);
#pragma unroll
      for (int j = 0; j < 16; ++j)
        *(float4*)&Tw[(2 * j + (lane >> 5)) * 136 + ((lane & 31) << 2)] = v[j];
      int NB = N >> 7, KB = K >> 5;
      u16* op = outw + ((size_t)(e * NB + nx) * KB + ky) * 4096;
#pragma unroll
      for (int h = 0; h < 2; ++h) {
        int nr = lane + h * 64;
        u32 o[16];
#pragma unroll
        for (int k2 = 0; k2 < 16; ++k2)
          o[k2] = pack2(Tw[(2 * k2) * 136 + nr], Tw[(2 * k2 + 1) * 136 + nr]);
        u16* opp = op + nr * 32;
        *(uint4*)opp        = *(uint4*)&o[0];
        *(uint4*)(opp + 8)  = *(uint4*)&o[4];
        *(uint4*)(opp + 16) = *(uint4*)&o[8];
        *(uint4*)(opp + 24) = *(uint4*)&o[12];
      }
    }
  } else if (bid < PREP_RT) {
    // ---- router: one wave per token; emits t2e/t2w + Xb bf16; NO atomics ----
    int lane = tid & 63;
    int t = (bid - PREP_WT) * 4 + (tid >> 6);
    const float* xr = x + (size_t)t * DMODEL;
    u16* xbr = xb + (size_t)t * DMODEL;
    float acc[8];
#pragma unroll
    for (int e = 0; e < 8; ++e) acc[e] = 0.f;
#pragma unroll
    for (int i = 0; i < 12; ++i) {
      int d = lane + (i << 6);
      float xd = xr[d];
      xbr[d] = f2b(xd);
      float4 g0 = *(const float4*)(gw + d * 8);
      float4 g1 = *(const float4*)(gw + d * 8 + 4);
      acc[0] += xd * g0.x; acc[1] += xd * g0.y;
      acc[2] += xd * g0.z; acc[3] += xd * g0.w;
      acc[4] += xd * g1.x; acc[5] += xd * g1.y;
      acc[6] += xd * g1.z; acc[7] += xd * g1.w;
    }
#pragma unroll
    for (int s = 32; s >= 1; s >>= 1) {
#pragma unroll
      for (int e = 0; e < 8; ++e) acc[e] += __shfl_xor(acc[e], s);
    }
    if (lane == 0) {
      int i0 = 0;
#pragma unroll
      for (int e = 1; e < 8; ++e) if (acc[e] > acc[i0]) i0 = e;
      int i1 = (i0 == 0) ? 1 : 0;
#pragma unroll
      for (int e = 0; e < 8; ++e) if (e != i0 && acc[e] > acc[i1]) i1 = e;
      float w0 = 1.f / (1.f + __expf(acc[i1] - acc[i0]));
      t2e[2 * t] = i0; t2e[2 * t + 1] = i1;
      t2w[2 * t] = w0; t2w[2 * t + 1] = 1.f - w0;
    }
  } else {
    // ---- zero out[] (stage2 accumulates into it atomically); 64B/thread ----
    int zid = bid - PREP_RT;
    float4 z = (float4){0.f, 0.f, 0.f, 0.f};
    float* p = out + ((size_t)zid * 256 + tid) * 16;
    *(float4*)p = z; *(float4*)(p + 4) = z;
    *(float4*)(p + 8) = z; *(float4*)(p + 12) = z;
  }
}

// ---------------- fused scan+scatter: 1 block, LDS atomics only ----------------
__global__ __launch_bounds__(1024) void k_scansc(
    const int* __restrict__ t2e, const float* __restrict__ t2w, int* __restrict__ meta,
    int* __restrict__ tok_of_row, int* __restrict__ slot_of, float* __restrict__ w_of_row,
    float* __restrict__ outp) {
  __shared__ int cnt[8], cur[8];
  int tid = threadIdx.x;
  if (tid < 8) cnt[tid] = 0;
  __syncthreads();
  int e0a[2], e1a[2];
#pragma unroll
  for (int j = 0; j < 2; ++j) {
    int t = tid + j * 1024;
    e0a[j] = t2e[2 * t]; e1a[j] = t2e[2 * t + 1];
    atomicAdd(&cnt[e0a[j]], 1); atomicAdd(&cnt[e1a[j]], 1);
  }
  __syncthreads();
  if (tid == 0) {
    int r = 0;
#pragma unroll 1
    for (int e = 0; e < NEXP; ++e) {
      int c = cnt[e];
      meta[M_CNT + e] = c; meta[M_OFF + e] = r; cur[e] = r; r += c;
    }
    meta[M_OFF + NEXP] = r;
    outp[(size_t)T_TOK * DMODEL] = 0.f;  // load_balancing_loss
  }
  __syncthreads();
#pragma unroll
  for (int j = 0; j < 2; ++j) {
    int t = tid + j * 1024;
    int s0 = atomicAdd(&cur[e0a[j]], 1);
    tok_of_row[s0] = t; slot_of[2 * t] = s0; w_of_row[s0] = t2w[2 * t];
    int s1 = atomicAdd(&cur[e1a[j]], 1);
    tok_of_row[s1] = t; slot_of[2 * t + 1] = s1; w_of_row[s1] = t2w[2 * t + 1];
  }
}

// ---------------- stage 1: Xb[tok] @ [WgB|WuB] -> H = silu(g)*u ----------------
// tile 128x128, BK=32, double-buffered LDS + counted vmcnt, swizzled granules.
// COMPACT grid + chunked XCD swizzle.  (R4-proven config)
__global__ __launch_bounds__(256, 3) void k_stage1b(
    const u16* __restrict__ Xb, const u16* __restrict__ WgB, const u16* __restrict__ WuB,
    const int* __restrict__ meta, const int* __restrict__ tok, u16* __restrict__ H) {
  __shared__ u16 Xs[2][4096];    // [buf][128 rows][32 k]   8KB/buf
  __shared__ u16 Wgs[2][4096];
  __shared__ u16 Wus[2][4096];
  int bid = blockIdx.x;
  int wid = (bid & 7) * G1_PERX + (bid >> 3);
  int e = 0, base = 0, Te = 0, off_e = 0, rows_e = 0;
#pragma unroll 1
  for (e = 0; e < NEXP; ++e) {
    off_e = meta[M_OFF + e];
    rows_e = meta[M_OFF + e + 1] - off_e;
    Te = (rows_e + 127) >> 7;
    int c = Te << 4;
    if (wid < base + c) break;
    base += c;
  }
  if (e == NEXP) return;   // contiguous dead tail of this XCD's slice
  int local = wid - base;
  int rb = local >> 4, fb = local & 15;
  int r0 = rb * 128;
  int rows_t = rows_e - r0; if (rows_t > 128) rows_t = 128;
  int f0 = fb * 128;
  int tid = threadIdx.x, lane = tid & 63, w = tid >> 6;
  int wr = w >> 1, wc = w & 1, q = lane >> 4, lm = lane & 15;

  int rsub = lane >> 2;
  int g4 = (lane & 3) ^ ((lane >> 3) & 3);
  int rA = w * 32 + rsub;
  int cA = (rA < rows_t) ? rA : (rows_t - 1);
  int cB = (rA + 16 < rows_t) ? (rA + 16) : (rows_t - 1);
  const u16* aG0 = Xb + (size_t)tok[off_e + r0 + cA] * DMODEL + g4 * 8;
  const u16* aG1 = Xb + (size_t)tok[off_e + r0 + cB] * DMODEL + g4 * 8;
  size_t cb = (size_t)((e * 16 + fb) * 24) * 4096 + w * 1024 + rsub * 32 + g4 * 8;
  const u16* gG = WgB + cb;
  const u16* uG = WuB + cb;

  int qx = (q ^ ((lm >> 1) & 3)) * 8;
  int aoff = (wr * 64 + lm) * 32 + qx;
  int boff = (wc * 64 + lm) * 32 + qx;

  f32x4 accg[4][4], accu[4][4];
#pragma unroll
  for (int i = 0; i < 4; ++i)
#pragma unroll
    for (int j = 0; j < 4; ++j) {
      accg[i][j] = (f32x4){0.f, 0.f, 0.f, 0.f};
      accu[i][j] = (f32x4){0.f, 0.f, 0.f, 0.f};
    }

  auto STG = [&](int b, int kko) {
    int ka = kko * 32;
    size_t kb = (size_t)kko * 4096;
    gl16(aG0 + ka, &Xs[b][w * 1024]);
    gl16(aG1 + ka, &Xs[b][w * 1024 + 512]);
    gl16(gG + kb, &Wgs[b][w * 1024]);
    gl16(gG + kb + 512, &Wgs[b][w * 1024 + 512]);
    gl16(uG + kb, &Wus[b][w * 1024]);
    gl16(uG + kb + 512, &Wus[b][w * 1024 + 512]);
  };
  auto CMP = [&](int b) {
    const u16* ap = &Xs[b][aoff];
    const u16* gp = &Wgs[b][boff];
    const u16* up = &Wus[b][boff];
    short8 af[4];
#pragma unroll
    for (int mt = 0; mt < 4; ++mt) af[mt] = *(const short8*)(ap + mt * 512);
#pragma unroll
    for (int nt = 0; nt < 4; ++nt) {
      short8 bg = *(const short8*)(gp + nt * 512);
      short8 bu = *(const short8*)(up + nt * 512);
#pragma unroll
      for (int mt = 0; mt < 4; ++mt) {
        accg[mt][nt] = __builtin_amdgcn_mfma_f32_16x16x32_bf16(af[mt], bg, accg[mt][nt], 0, 0, 0);
        accu[mt][nt] = __builtin_amdgcn_mfma_f32_16x16x32_bf16(af[mt], bu, accu[mt][nt], 0, 0, 0);
      }
    }
  };

  STG(0, 0);
  for (int kko = 0; kko < 23; ++kko) {
    STG((kko + 1) & 1, kko + 1);
    asm volatile("s_waitcnt vmcnt(6)" ::: "memory");  // prev tile landed; 6 new stay in flight
    __builtin_amdgcn_s_barrier();
    asm volatile("" ::: "memory");
    CMP(kko & 1);
    asm volatile("s_waitcnt lgkmcnt(0)" ::: "memory");
    __builtin_amdgcn_s_barrier();
    asm volatile("" ::: "memory");
  }
  asm volatile("s_waitcnt vmcnt(0)" ::: "memory");
  __builtin_amdgcn_s_barrier();
  asm volatile("" ::: "memory");
  CMP(1);  // kko = 23

#pragma unroll
  for (int mt = 0; mt < 4; ++mt)
#pragma unroll
    for (int r = 0; r < 4; ++r) {
      int lrow = wr * 64 + mt * 16 + q * 4 + r;
      if (lrow < rows_t) {
        size_t rowbase = (size_t)(off_e + r0 + lrow) * DFF + f0 + wc * 64;
#pragma unroll
        for (int nt = 0; nt < 4; ++nt) {
          float g = accg[mt][nt][r], u = accu[mt][nt][r];
          float h = g / (1.f + __expf(-g)) * u;
          H[rowbase + nt * 16 + lm] = f2b(h);
        }
      }
    }
}

// ---------------- stage 2: H @ WdB -> atomicAdd into out (combine fused) --------
// tile 64x128, BK=64, double-buffered + counted vmcnt, swizzled granules.
__global__ __launch_bounds__(256, 3) void k_stage2b(
    const u16* __restrict__ H, const u16* __restrict__ WdB,
    const int* __restrict__ meta, const int* __restrict__ tok,
    const float* __restrict__ wrow, float* __restrict__ out) {
  __shared__ u16 As[2][4096];
  __shared__ u16 Ws[2][8192];
  int bid = blockIdx.x;
  int wid = (bid & 7) * G2_PERX + (bid >> 3);
  int e = 0, base = 0, off_e = 0, rows_e = 0;
#pragma unroll 1
  for (e = 0; e < NEXP; ++e) {
    off_e = meta[M_OFF + e];
    rows_e = meta[M_OFF + e + 1] - off_e;
    int Tr = (rows_e + 63) >> 6;
    int c = Tr * 6;
    if (wid < base + c) break;
    base += c;
  }
  if (e == NEXP) return;
  int local = wid - base;
  int rb = (int)(((unsigned)local * 43691u) >> 18);   // local / 6
  int nb = local - rb * 6;
  int r0 = rb * 64;
  int rows_t = rows_e - r0; if (rows_t > 64) rows_t = 64;
  int n0 = nb * 128;
  int tid = threadIdx.x, lane = tid & 63, w = tid >> 6;
  int q = lane >> 4, lm = lane & 15;

  int rsub = lane >> 2;
  int g4 = (lane & 3) ^ ((lane >> 3) & 3);
  int rA = w * 16 + rsub;
  int cA = (rA < rows_t) ? rA : (rows_t - 1);
  const u16* aG = H + (size_t)(off_e + r0 + cA) * DFF + g4 * 8;
  size_t cb = (size_t)((e * 6 + nb) * 64) * 4096 + w * 1024 + rsub * 32 + g4 * 8;
  const u16* wG = WdB + cb;

  int qx = (q ^ ((lm >> 1) & 3)) * 8;
  int aoff = lm * 32 + qx;
  int boff = (w * 32 + lm) * 32 + qx;

  f32x4 acc[4][2];
#pragma unroll
  for (int i = 0; i < 4; ++i)
#pragma unroll
    for (int j = 0; j < 2; ++j) acc[i][j] = (f32x4){0.f, 0.f, 0.f, 0.f};

  auto STG = [&](int b, int kko) {
    int ka = kko * 64;
    size_t kb = (size_t)kko * 8192;
    gl16(aG + ka, &As[b][w * 512]);
    gl16(aG + ka + 32, &As[b][2048 + w * 512]);
    gl16(wG + kb, &Ws[b][w * 1024]);
    gl16(wG + kb + 512, &Ws[b][w * 1024 + 512]);
    gl16(wG + kb + 4096, &Ws[b][4096 + w * 1024]);
    gl16(wG + kb + 4608, &Ws[b][4096 + w * 1024 + 512]);
  };
  auto CMP = [&](int b) {
    const u16* ap = &As[b][aoff];
    const u16* bp = &Ws[b][boff];
#pragma unroll
    for (int s = 0; s < 2; ++s) {
      short8 af[4];
#pragma unroll
      for (int mt = 0; mt < 4; ++mt) af[mt] = *(const short8*)(ap + s * 2048 + mt * 512);
#pragma unroll
      for (int nt = 0; nt < 2; ++nt) {
        short8 bb = *(const short8*)(bp + s * 4096 + nt * 512);
#pragma unroll
        for (int mt = 0; mt < 4; ++mt)
          acc[mt][nt] = __builtin_amdgcn_mfma_f32_16x16x32_bf16(af[mt], bb, acc[mt][nt], 0, 0, 0);
      }
    }
  };

  STG(0, 0);
  for (int kko = 0; kko < 31; ++kko) {
    STG((kko + 1) & 1, kko + 1);
    asm volatile("s_waitcnt vmcnt(6)" ::: "memory");
    __builtin_amdgcn_s_barrier();
    asm volatile("" ::: "memory");
    CMP(kko & 1);
    asm volatile("s_waitcnt lgkmcnt(0)" ::: "memory");
    __builtin_amdgcn_s_barrier();
    asm volatile("" ::: "memory");
  }
  asm volatile("s_waitcnt vmcnt(0)" ::: "memory");
  __builtin_amdgcn_s_barrier();
  asm volatile("" ::: "memory");
  CMP(1);  // kko = 31

#pragma unroll
  for (int mt = 0; mt < 4; ++mt)
#pragma unroll
    for (int r = 0; r < 4; ++r) {
      int lrow = mt * 16 + q * 4 + r;
      if (lrow < rows_t) {
        int row = off_e + r0 + lrow;
        int token = tok[row];
        float wgt = wrow[row];
        float* ob = out + (size_t)token * DMODEL + n0 + w * 32;
#pragma unroll
        for (int nt = 0; nt < 2; ++nt)
          atomicAdd(&ob[nt * 16 + lm], wgt * acc[mt][nt][r]);
      }
    }
}

// ---------------- combine (fallback path only) ----------------
__global__ __launch_bounds__(192) void k_combine(
    const float* __restrict__ Op, const int* __restrict__ slot_of,
    const float* __restrict__ t2w, float* __restrict__ out) {
  int t = blockIdx.x;
  int d4 = threadIdx.x << 2;
  int s0 = slot_of[2 * t], s1 = slot_of[2 * t + 1];
  float w0 = t2w[2 * t], w1 = t2w[2 * t + 1];
  float4 a = *(const float4*)&Op[(size_t)s0 * DMODEL + d4];
  float4 b = *(const float4*)&Op[(size_t)s1 * DMODEL + d4];
  float4 r;
  r.x = w0 * a.x + w1 * b.x;
  r.y = w0 * a.y + w1 * b.y;
  r.z = w0 * a.z + w1 * b.z;
  r.w = w0 * a.w + w1 * b.w;
  *(float4*)&out[(size_t)t * DMODEL + d4] = r;
}

// ---------------- router (fallback path only; no atomics) ----------------
__global__ __launch_bounds__(256) void k_router_fb(
    const float* __restrict__ x, const float* __restrict__ gw,
    int* __restrict__ t2e, float* __restrict__ t2w, u16* __restrict__ xb) {
  int lane = threadIdx.x & 63;
  int t = blockIdx.x * 4 + (threadIdx.x >> 6);
  const float* xr = x + (size_t)t * DMODEL;
  u16* xbr = xb + (size_t)t * DMODEL;
  float acc[8];
#pragma unroll
  for (int e = 0; e < 8; ++e) acc[e] = 0.f;
#pragma unroll
  for (int i = 0; i < 12; ++i) {
    int d = lane + (i << 6);
    float xd = xr[d];
    xbr[d] = f2b(xd);
    float4 g0 = *(const float4*)(gw + d * 8);
    float4 g1 = *(const float4*)(gw + d * 8 + 4);
    acc[0] += xd * g0.x; acc[1] += xd * g0.y;
    acc[2] += xd * g0.z; acc[3] += xd * g0.w;
    acc[4] += xd * g1.x; acc[5] += xd * g1.y;
    acc[6] += xd * g1.z; acc[7] += xd * g1.w;
  }
#pragma unroll
  for (int s = 32; s >= 1; s >>= 1) {
#pragma unroll
    for (int e = 0; e < 8; ++e) acc[e] += __shfl_xor(acc[e], s);
  }
  if (lane == 0) {
    int i0 = 0;
#pragma unroll
    for (int e = 1; e < 8; ++e) if (acc[e] > acc[i0]) i0 = e;
    int i1 = (i0 == 0) ? 1 : 0;
#pragma unroll
    for (int e = 0; e < 8; ++e) if (e != i0 && acc[e] > acc[i1]) i1 = e;
    float w0 = 1.f / (1.f + __expf(acc[i1] - acc[i0]));
    t2e[2 * t] = i0; t2e[2 * t + 1] = i1;
    t2w[2 * t] = w0; t2w[2 * t + 1] = 1.f - w0;
  }
}

// ================= fallback (fp32 direct) =================
__device__ __forceinline__ void wpack(u32* lds, int k2, int n8, uint4 a, uint4 b) {
  int idx = n8 * WSTR + k2;
  lds[idx + 0 * WSTR] = (a.x & 0xffffu) | (b.x << 16);
  lds[idx + 1 * WSTR] = (a.x >> 16) | (b.x & 0xffff0000u);
  lds[idx + 2 * WSTR] = (a.y & 0xffffu) | (b.y << 16);
  lds[idx + 3 * WSTR] = (a.y >> 16) | (b.y & 0xffff0000u);
  lds[idx + 4 * WSTR] = (a.z & 0xffffu) | (b.z << 16);
  lds[idx + 5 * WSTR] = (a.z >> 16) | (b.z & 0xffff0000u);
  lds[idx + 6 * WSTR] = (a.w & 0xffffu) | (b.w << 16);
  lds[idx + 7 * WSTR] = (a.w >> 16) | (b.w & 0xffff0000u);
}

__global__ __launch_bounds__(256) void k_stage1f(
    const float* __restrict__ xv, const float* __restrict__ wgv, const float* __restrict__ wuv,
    const int* __restrict__ meta, const int* __restrict__ tok, u16* __restrict__ H) {
  __shared__ u16 Xs[64 * 32];
  __shared__ u16 Wgs[128 * BKP];
  __shared__ u16 Wus[128 * BKP];
  int e = blockIdx.z;
  int off_e = meta[M_OFF + e];
  int rows_e = meta[M_OFF + e + 1] - off_e;
  int r0 = blockIdx.y * 64;
  if (r0 >= rows_e) return;
  int rows_t = rows_e - r0; if (rows_t > 64) rows_t = 64;
  int f0 = blockIdx.x * 128;
  int tid = threadIdx.x, lane = tid & 63, w = tid >> 6;
  int wr = w >> 1, wc = w & 1;
  int srow = (w << 4) + (lane >> 2);
  int trow = (srow < rows_t) ? tok[off_e + r0 + srow] : tok[off_e];
  int xcol = (lane & 3) << 3;
  u16* xl = &Xs[srow * 32 + xcol];
  int k2 = tid >> 4, n8 = (tid & 15) << 3;
  size_t wbase = (size_t)e * (DMODEL * DFF) + (size_t)(k2 << 1) * DFF + f0 + n8;
  f32x4 accg[2][4], accu[2][4];
#pragma unroll
  for (int i = 0; i < 2; ++i)
#pragma unroll
    for (int j = 0; j < 4; ++j) {
      accg[i][j] = (f32x4){0.f, 0.f, 0.f, 0.f};
      accu[i][j] = (f32x4){0.f, 0.f, 0.f, 0.f};
    }
  for (int kk = 0; kk < DMODEL / 32; ++kk) {
    int k0 = kk << 5;
    const float* xg = xv + (size_t)trow * DMODEL + xcol;
    const float* wgp = wgv + wbase;
    const float* wup = wuv + wbase;
    uint4 xa = cvt8(*(const float4*)(xg + k0), *(const float4*)(xg + k0 + 4));
    uint4 ga = cvt8(*(const float4*)(wgp + (size_t)k0 * DFF), *(const float4*)(wgp + (size_t)k0 * DFF + 4));
    uint4 gb = cvt8(*(const float4*)(wgp + (size_t)k0 * DFF + DFF), *(const float4*)(wgp + (size_t)k0 * DFF + DFF + 4));
    uint4 ua = cvt8(*(const float4*)(wup + (size_t)k0 * DFF), *(const float4*)(wup + (size_t)k0 * DFF + 4));
    uint4 ub = cvt8(*(const float4*)(wup + (size_t)k0 * DFF + DFF), *(const float4*)(wup + (size_t)k0 * DFF + DFF + 4));
    __syncthreads();
    *(uint4*)xl = xa;
    wpack((u32*)Wgs, k2, n8, ga, gb);
    wpack((u32*)Wus, k2, n8, ua, ub);
    __syncthreads();
    short8 af[2];
#pragma unroll
    for (int mt = 0; mt < 2; ++mt)
      af[mt] = *(const short8*)&Xs[((wr << 5) + (mt << 4) + (lane & 15)) * 32 + ((lane >> 4) << 3)];
#pragma unroll
    for (int nt = 0; nt < 4; ++nt) {
      int col = (wc << 6) + (nt << 4) + (lane & 15);
      short8 bg = *(const short8*)&Wgs[col * BKP + ((lane >> 4) << 3)];
      short8 bu = *(const short8*)&Wus[col * BKP + ((lane >> 4) << 3)];
#pragma unroll
      for (int mt = 0; mt < 2; ++mt) {
        accg[mt][nt] = __builtin_amdgcn_mfma_f32_16x16x32_bf16(af[mt], bg, accg[mt][nt], 0, 0, 0);
        accu[mt][nt] = __builtin_amdgcn_mfma_f32_16x16x32_bf16(af[mt], bu, accu[mt][nt], 0, 0, 0);
      }
    }
  }
  int q = lane >> 4, c = lane & 15;
#pragma unroll
  for (int mt = 0; mt < 2; ++mt)
#pragma unroll
    for (int r = 0; r < 4; ++r) {
      int lrow = (wr << 5) + (mt << 4) + (q << 2) + r;
      if (lrow < rows_t) {
        size_t rowbase = (size_t)(off_e + r0 + lrow) * DFF + f0 + (wc << 6);
#pragma unroll
        for (int nt = 0; nt < 4; ++nt) {
          float g = accg[mt][nt][r], u = accu[mt][nt][r];
          float h = g / (1.f + __expf(-g)) * u;
          H[rowbase + (nt << 4) + c] = f2b(h);
        }
      }
    }
}

__global__ __launch_bounds__(256) void k_stage2f(
    const u16* __restrict__ H, const float* __restrict__ wdv,
    const int* __restrict__ meta, float* __restrict__ Op) {
  __shared__ u16 As[64 * 32];
  __shared__ u16 Ws[128 * BKP];
  int e = blockIdx.z;
  int off_e = meta[M_OFF + e];
  int rows_e = meta[M_OFF + e + 1] - off_e;
  int r0 = blockIdx.y * 64;
  if (r0 >= rows_e) return;
  int rows_t = rows_e - r0; if (rows_t > 64) rows_t = 64;
  int n0 = blockIdx.x * 128;
  int tid = threadIdx.x, lane = tid & 63, w = tid >> 6;
  int wr = w >> 1, wc = w & 1;
  int srow = (w << 4) + (lane >> 2);
  int hrow = off_e + r0 + ((srow < rows_t) ? srow : 0);
  const u16* ag = H + (size_t)hrow * DFF + ((lane & 3) << 3);
  u16* al = &As[srow * 32 + ((lane & 3) << 3)];
  int k2 = tid >> 4, n8 = (tid & 15) << 3;
  size_t wbase = (size_t)e * (DFF * DMODEL) + (size_t)(k2 << 1) * DMODEL + n0 + n8;
  f32x4 acc[2][4];
#pragma unroll
  for (int i = 0; i < 2; ++i)
#pragma unroll
    for (int j = 0; j < 4; ++j) acc[i][j] = (f32x4){0.f, 0.f, 0.f, 0.f};
  for (int kk = 0; kk < DFF / 32; ++kk) {
    int k0 = kk << 5;
    uint4 xa = *(const uint4*)(ag + k0);
    const float* wdp = wdv + wbase;
    uint4 ga = cvt8(*(const float4*)(wdp + (size_t)k0 * DMODEL), *(const float4*)(wdp + (size_t)k0 * DMODEL + 4));
    uint4 gb = cvt8(*(const float4*)(wdp + (size_t)k0 * DMODEL + DMODEL), *(const float4*)(wdp + (size_t)k0 * DMODEL + DMODEL + 4));
    __syncthreads();
    *(uint4*)al = xa;
    wpack((u32*)Ws, k2, n8, ga, gb);
    __syncthreads();
    short8 af[2];
#pragma unroll
    for (int mt = 0; mt < 2; ++mt)
      af[mt] = *(const short8*)&As[((wr << 5) + (mt << 4) + (lane & 15)) * 32 + ((lane >> 4) << 3)];
#pragma unroll
    for (int nt = 0; nt < 4; ++nt) {
      int col = (wc << 6) + (nt << 4) + (lane & 15);
      short8 b = *(const short8*)&Ws[col * BKP + ((lane >> 4) << 3)];
#pragma unroll
      for (int mt = 0; mt < 2; ++mt)
        acc[mt][nt] = __builtin_amdgcn_mfma_f32_16x16x32_bf16(af[mt], b, acc[mt][nt], 0, 0, 0);
    }
  }
  int q = lane >> 4, c = lane & 15;
#pragma unroll
  for (int mt = 0; mt < 2; ++mt)
#pragma unroll
    for (int r = 0; r < 4; ++r) {
      int lrow = (wr << 5) + (mt << 4) + (q << 2) + r;
      if (lrow < rows_t) {
        size_t rowbase = (size_t)(off_e + r0 + lrow) * DMODEL + n0 + (wc << 6);
#pragma unroll
        for (int nt = 0; nt < 4; ++nt)
          Op[rowbase + (nt << 4) + c] = acc[mt][nt][r];
      }
    }
}

extern "C" void kernel_launch(void* const* d_in, const int* in_sizes, int n_in,
                              void* d_out, int out_size, void* d_ws, size_t ws_size,
                              hipStream_t stream) {
  const float* x  = (const float*)d_in[0];
  const float* gw = (const float*)d_in[1];
  const float* wg = (const float*)d_in[2];
  const float* wu = (const float*)d_in[3];
  const float* wd = (const float*)d_in[4];
  float* out = (float*)d_out;

  char* ws = (char*)d_ws;
  int* meta = (int*)ws;
  int* t2e        = (int*)(ws + 256);
  int* slot_of    = (int*)(ws + 16640);
  int* tok_of_row = (int*)(ws + 33024);
  float* t2w      = (float*)(ws + 49408);
  u16* Xb         = (u16*)(ws + 65792);                 // [2048*768] bf16

  const size_t NEED = 108069120;  // fast-path ws footprint
  if (ws_size >= NEED) {
    u16* H         = (u16*)(ws + 3211520);            // [4096*2048] bf16
    float* w_of_row = (float*)(ws + 19988736);        // [4096] fp32 (Op area reuse)
    u16* WgB   = (u16*)(ws + 32571648);               // blocked bf16
    u16* WuB   = (u16*)(ws + 57737472);
    u16* WdB   = (u16*)(ws + 82903296);

    // 4 launches total
    k_prep<<<PREP_GRID, 256, 0, stream>>>(wg, wu, wd, x, gw, WgB, WuB, WdB,
                                          t2e, t2w, Xb, out);
    k_scansc<<<1, 1024, 0, stream>>>(t2e, t2w, meta, tok_of_row, slot_of, w_of_row, out);
    k_stage1b<<<G1_GRID, 256, 0, stream>>>(Xb, WgB, WuB, meta, tok_of_row, H);
    k_stage2b<<<G2_GRID, 256, 0, stream>>>(H, WdB, meta, tok_of_row, w_of_row, out);
  } else {
    u16* H    = (u16*)(ws + 65792);
    float* Op = (float*)(ws + 65792 + 16777216);
    float* w_of_row = (float*)(ws + 65792 + 16777216 + 12582912);
    k_router_fb<<<T_TOK / 4, 256, 0, stream>>>(x, gw, t2e, t2w, Xb);
    k_scansc<<<1, 1024, 0, stream>>>(t2e, t2w, meta, tok_of_row, slot_of, w_of_row, out);
    dim3 g1(DFF / 128, T_TOK / 64, NEXP);
    k_stage1f<<<g1, 256, 0, stream>>>(x, wg, wu, meta, tok_of_row, H);
    dim3 g2(DMODEL / 128, T_TOK / 64, NEXP);
    k_stage2f<<<g2, 256, 0, stream>>>(H, wd, meta, Op);
    k_combine<<<T_TOK, 192, 0, stream>>>(Op, slot_of, t2w, out);
  }
}

// Round 11
// 254.941 us; speedup vs baseline: 1.0687x; 1.0687x over previous
//
#include <hip/hip_runtime.h>
#include <stdint.h>

typedef __attribute__((ext_vector_type(8))) short short8;
typedef __attribute__((ext_vector_type(4))) float f32x4;
typedef unsigned int u32;
typedef unsigned short u16;

#define T_TOK 2048
#define DMODEL 768
#define DFF 2048
#define NEXP 8

#define BKP 40      // (fallback path) padded LDS row stride
#define WSTR 20     // (fallback wpack) uint stride per n-column

// meta ints: [0..7]=cnt [8..15]=cur [16..24]=off
#define M_CNT 0
#define M_CUR 8
#define M_OFF 16

// compact grids: worst-case tile counts (sum rows = 4096)
#define G1_GRID 640   // sum ceil(rows_e/128)*16 <= (32+8)*16 = 640 ; 80/XCD
#define G1_PERX 80
#define G2_GRID 432   // sum ceil(rows_e/64)*6 <= (64+8)*6 = 432 ; 54/XCD
#define G2_PERX 54
#define S1_GRID (G1_GRID + 3072)   // stage1 gemm blocks + wd-transpose blocks

// k_prep grid: simple one-tile wtrans for wg+wu || router || zero(out)
#define PREP_WT 6144                // 2 x 3072 one-tile wtrans blocks
#define PREP_RT (PREP_WT + 512)     // router blocks
#define PREP_GRID (PREP_RT + 384)   // zero blocks: 384*256*64B = 6291456B = out

__device__ __forceinline__ float b2f(u16 u) {
  union { u32 i; float f; } v; v.i = ((u32)u) << 16; return v.f;
}
__device__ __forceinline__ u16 f2b(float f) {
  union { float f; u32 i; } v; v.f = f;
  return (u16)((v.i + 0x7fffu + ((v.i >> 16) & 1u)) >> 16);
}
__device__ __forceinline__ u32 pack2(float lo, float hi) {
  return (u32)f2b(lo) | ((u32)f2b(hi) << 16);
}
__device__ __forceinline__ uint4 cvt8(float4 a, float4 b) {
  uint4 r; r.x = pack2(a.x, a.y); r.y = pack2(a.z, a.w);
  r.z = pack2(b.x, b.y); r.w = pack2(b.z, b.w); return r;
}
// async global->LDS, 16B per lane; LDS dst = wave-uniform base + lane*16
__device__ __forceinline__ void gl16(const u16* g, u16* l) {
  __builtin_amdgcn_global_load_lds((const __attribute__((address_space(1))) void*)g,
                                   (__attribute__((address_space(3))) void*)l, 16, 0, 0);
}

// ---------------- prep: simple wtrans (wg,wu) || router || zero(out) ----------------
// measured-best wtrans structure (R4: 69us for 3 tensors); wd moved to stage1 launch.
__global__ __launch_bounds__(256) void k_prep(
    const float* __restrict__ wg, const float* __restrict__ wu,
    const float* __restrict__ x, const float* __restrict__ gw,
    u16* __restrict__ WgB, u16* __restrict__ WuB,
    int* __restrict__ t2e, float* __restrict__ t2w, u16* __restrict__ xb,
    float* __restrict__ out) {
  __shared__ float T[32][136];
  int bid = blockIdx.x;
  int tid = threadIdx.x;
  if (bid < PREP_WT) {
    // ---- weight transpose -> blocked bf16 [e][16][24][128][32] (K=768,N=2048)
    const float* in; u16* outw; int b;
    if (bid < 3072) { in = wg; outw = WgB; b = bid; }
    else { in = wu; outw = WuB; b = bid - 3072; }
    int nx = b & 15; int r = b >> 4;
    int e = (int)(((unsigned)r * 43691u) >> 20);   // r/24, r<192
    int ky = r - e * 24;
    const float* ip = in + (size_t)e * (768 * 2048) + (size_t)(ky * 32) * 2048 + nx * 128;
    int kr = tid >> 3, nc = (tid & 7) * 16;
    const float* rp = ip + (size_t)kr * 2048 + nc;
    float4 v0 = *(const float4*)(rp);
    float4 v1 = *(const float4*)(rp + 4);
    float4 v2 = *(const float4*)(rp + 8);
    float4 v3 = *(const float4*)(rp + 12);
    *(float4*)&T[kr][nc] = v0;
    *(float4*)&T[kr][nc + 4] = v1;
    *(float4*)&T[kr][nc + 8] = v2;
    *(float4*)&T[kr][nc + 12] = v3;
    __syncthreads();
    int nr = tid >> 1, kh = (tid & 1) * 16;
    float v[16];
#pragma unroll
    for (int j = 0; j < 16; ++j) v[j] = T[kh + j][nr];
    uint4 o0, o1;
    o0.x = pack2(v[0], v[1]);  o0.y = pack2(v[2], v[3]);
    o0.z = pack2(v[4], v[5]);  o0.w = pack2(v[6], v[7]);
    o1.x = pack2(v[8], v[9]);  o1.y = pack2(v[10], v[11]);
    o1.z = pack2(v[12], v[13]); o1.w = pack2(v[14], v[15]);
    u16* op = outw + ((size_t)(e * 16 + nx) * 24 + ky) * 4096 + nr * 32 + kh;
    *(uint4*)op = o0;
    *(uint4*)(op + 8) = o1;
  } else if (bid < PREP_RT) {
    // ---- router: one wave per token; emits t2e/t2w + Xb bf16; NO atomics ----
    int lane = tid & 63;
    int t = (bid - PREP_WT) * 4 + (tid >> 6);
    const float* xr = x + (size_t)t * DMODEL;
    u16* xbr = xb + (size_t)t * DMODEL;
    float acc[8];
#pragma unroll
    for (int e = 0; e < 8; ++e) acc[e] = 0.f;
#pragma unroll
    for (int i = 0; i < 12; ++i) {
      int d = lane + (i << 6);
      float xd = xr[d];
      xbr[d] = f2b(xd);
      float4 g0 = *(const float4*)(gw + d * 8);
      float4 g1 = *(const float4*)(gw + d * 8 + 4);
      acc[0] += xd * g0.x; acc[1] += xd * g0.y;
      acc[2] += xd * g0.z; acc[3] += xd * g0.w;
      acc[4] += xd * g1.x; acc[5] += xd * g1.y;
      acc[6] += xd * g1.z; acc[7] += xd * g1.w;
    }
#pragma unroll
    for (int s = 32; s >= 1; s >>= 1) {
#pragma unroll
      for (int e = 0; e < 8; ++e) acc[e] += __shfl_xor(acc[e], s);
    }
    if (lane == 0) {
      int i0 = 0;
#pragma unroll
      for (int e = 1; e < 8; ++e) if (acc[e] > acc[i0]) i0 = e;
      int i1 = (i0 == 0) ? 1 : 0;
#pragma unroll
      for (int e = 0; e < 8; ++e) if (e != i0 && acc[e] > acc[i1]) i1 = e;
      float w0 = 1.f / (1.f + __expf(acc[i1] - acc[i0]));
      t2e[2 * t] = i0; t2e[2 * t + 1] = i1;
      t2w[2 * t] = w0; t2w[2 * t + 1] = 1.f - w0;
    }
  } else {
    // ---- zero out[] (stage2 accumulates into it atomically); 64B/thread ----
    int zid = bid - PREP_RT;
    float4 z = (float4){0.f, 0.f, 0.f, 0.f};
    float* p = out + ((size_t)zid * 256 + tid) * 16;
    *(float4*)p = z; *(float4*)(p + 4) = z;
    *(float4*)(p + 8) = z; *(float4*)(p + 12) = z;
  }
}

// ---------------- fused scan+scatter: 1 block, LDS atomics only ----------------
__global__ __launch_bounds__(1024) void k_scansc(
    const int* __restrict__ t2e, const float* __restrict__ t2w, int* __restrict__ meta,
    int* __restrict__ tok_of_row, int* __restrict__ slot_of, float* __restrict__ w_of_row,
    float* __restrict__ outp) {
  __shared__ int cnt[8], cur[8];
  int tid = threadIdx.x;
  if (tid < 8) cnt[tid] = 0;
  __syncthreads();
  int e0a[2], e1a[2];
#pragma unroll
  for (int j = 0; j < 2; ++j) {
    int t = tid + j * 1024;
    e0a[j] = t2e[2 * t]; e1a[j] = t2e[2 * t + 1];
    atomicAdd(&cnt[e0a[j]], 1); atomicAdd(&cnt[e1a[j]], 1);
  }
  __syncthreads();
  if (tid == 0) {
    int r = 0;
#pragma unroll 1
    for (int e = 0; e < NEXP; ++e) {
      int c = cnt[e];
      meta[M_CNT + e] = c; meta[M_OFF + e] = r; cur[e] = r; r += c;
    }
    meta[M_OFF + NEXP] = r;
    outp[(size_t)T_TOK * DMODEL] = 0.f;  // load_balancing_loss
  }
  __syncthreads();
#pragma unroll
  for (int j = 0; j < 2; ++j) {
    int t = tid + j * 1024;
    int s0 = atomicAdd(&cur[e0a[j]], 1);
    tok_of_row[s0] = t; slot_of[2 * t] = s0; w_of_row[s0] = t2w[2 * t];
    int s1 = atomicAdd(&cur[e1a[j]], 1);
    tok_of_row[s1] = t; slot_of[2 * t + 1] = s1; w_of_row[s1] = t2w[2 * t + 1];
  }
}

// ---------------- stage 1 (fused with wd-transpose): ----------------
// bid < G1_GRID : Xb[tok] @ [WgB|WuB] -> H   (R4-proven 128x128 BK=32 dbuf config)
// bid >= G1_GRID: wd fp32 -> WdB blocked bf16 (one 32x128 tile; overlaps gemm --
//                 WdB is only consumed by stage2, next launch; stream-ordered).
__global__ __launch_bounds__(256, 3) void k_stage1b(
    const u16* __restrict__ Xb, const u16* __restrict__ WgB, const u16* __restrict__ WuB,
    const int* __restrict__ meta, const int* __restrict__ tok, u16* __restrict__ H,
    const float* __restrict__ wd, u16* __restrict__ WdB) {
  __shared__ __align__(16) char smem[49152];
  int bid = blockIdx.x;
  int tid = threadIdx.x;
  if (bid >= G1_GRID) {
    // ---- wd transpose: one 32x128 tile (K=2048, N=768) ----
    float (*T)[136] = (float(*)[136])smem;    // 17408B of the 48KB block
    int b = bid - G1_GRID;                    // [0, 3072)
    int qq = (int)(((unsigned)b * 43691u) >> 18);  // b/6
    int nx = b - qq * 6, ky = qq & 63, e = qq >> 6;
    const float* ip = wd + (size_t)e * (2048 * 768) + (size_t)(ky * 32) * 768 + nx * 128;
    int kr = tid >> 3, nc = (tid & 7) * 16;
    const float* rp = ip + (size_t)kr * 768 + nc;
    float4 v0 = *(const float4*)(rp);
    float4 v1 = *(const float4*)(rp + 4);
    float4 v2 = *(const float4*)(rp + 8);
    float4 v3 = *(const float4*)(rp + 12);
    *(float4*)&T[kr][nc] = v0;
    *(float4*)&T[kr][nc + 4] = v1;
    *(float4*)&T[kr][nc + 8] = v2;
    *(float4*)&T[kr][nc + 12] = v3;
    __syncthreads();
    int nr = tid >> 1, kh = (tid & 1) * 16;
    float v[16];
#pragma unroll
    for (int j = 0; j < 16; ++j) v[j] = T[kh + j][nr];
    uint4 o0, o1;
    o0.x = pack2(v[0], v[1]);  o0.y = pack2(v[2], v[3]);
    o0.z = pack2(v[4], v[5]);  o0.w = pack2(v[6], v[7]);
    o1.x = pack2(v[8], v[9]);  o1.y = pack2(v[10], v[11]);
    o1.z = pack2(v[12], v[13]); o1.w = pack2(v[14], v[15]);
    u16* op = WdB + ((size_t)(e * 6 + nx) * 64 + ky) * 4096 + nr * 32 + kh;
    *(uint4*)op = o0;
    *(uint4*)(op + 8) = o1;
    return;
  }
  // ---- gemm path ----
  u16* XsB  = (u16*)smem;            // [2][4096]
  u16* WgsB = (u16*)(smem + 16384);  // [2][4096]
  u16* WusB = (u16*)(smem + 32768);  // [2][4096]
  int wid = (bid & 7) * G1_PERX + (bid >> 3);
  int e = 0, base = 0, Te = 0, off_e = 0, rows_e = 0;
#pragma unroll 1
  for (e = 0; e < NEXP; ++e) {
    off_e = meta[M_OFF + e];
    rows_e = meta[M_OFF + e + 1] - off_e;
    Te = (rows_e + 127) >> 7;
    int c = Te << 4;
    if (wid < base + c) break;
    base += c;
  }
  if (e == NEXP) return;   // contiguous dead tail of this XCD's slice
  int local = wid - base;
  int rb = local >> 4, fb = local & 15;
  int r0 = rb * 128;
  int rows_t = rows_e - r0; if (rows_t > 128) rows_t = 128;
  int f0 = fb * 128;
  int lane = tid & 63, w = tid >> 6;
  int wr = w >> 1, wc = w & 1, q = lane >> 4, lm = lane & 15;

  int rsub = lane >> 2;
  int g4 = (lane & 3) ^ ((lane >> 3) & 3);
  int rA = w * 32 + rsub;
  int cA = (rA < rows_t) ? rA : (rows_t - 1);
  int cB = (rA + 16 < rows_t) ? (rA + 16) : (rows_t - 1);
  const u16* aG0 = Xb + (size_t)tok[off_e + r0 + cA] * DMODEL + g4 * 8;
  const u16* aG1 = Xb + (size_t)tok[off_e + r0 + cB] * DMODEL + g4 * 8;
  size_t cb = (size_t)((e * 16 + fb) * 24) * 4096 + w * 1024 + rsub * 32 + g4 * 8;
  const u16* gG = WgB + cb;
  const u16* uG = WuB + cb;

  int qx = (q ^ ((lm >> 1) & 3)) * 8;
  int aoff = (wr * 64 + lm) * 32 + qx;
  int boff = (wc * 64 + lm) * 32 + qx;

  f32x4 accg[4][4], accu[4][4];
#pragma unroll
  for (int i = 0; i < 4; ++i)
#pragma unroll
    for (int j = 0; j < 4; ++j) {
      accg[i][j] = (f32x4){0.f, 0.f, 0.f, 0.f};
      accu[i][j] = (f32x4){0.f, 0.f, 0.f, 0.f};
    }

  auto STG = [&](int b, int kko) {
    int ka = kko * 32;
    size_t kb = (size_t)kko * 4096;
    gl16(aG0 + ka, XsB + b * 4096 + w * 1024);
    gl16(aG1 + ka, XsB + b * 4096 + w * 1024 + 512);
    gl16(gG + kb, WgsB + b * 4096 + w * 1024);
    gl16(gG + kb + 512, WgsB + b * 4096 + w * 1024 + 512);
    gl16(uG + kb, WusB + b * 4096 + w * 1024);
    gl16(uG + kb + 512, WusB + b * 4096 + w * 1024 + 512);
  };
  auto CMP = [&](int b) {
    const u16* ap = XsB + b * 4096 + aoff;
    const u16* gp = WgsB + b * 4096 + boff;
    const u16* up = WusB + b * 4096 + boff;
    short8 af[4];
#pragma unroll
    for (int mt = 0; mt < 4; ++mt) af[mt] = *(const short8*)(ap + mt * 512);
#pragma unroll
    for (int nt = 0; nt < 4; ++nt) {
      short8 bg = *(const short8*)(gp + nt * 512);
      short8 bu = *(const short8*)(up + nt * 512);
#pragma unroll
      for (int mt = 0; mt < 4; ++mt) {
        accg[mt][nt] = __builtin_amdgcn_mfma_f32_16x16x32_bf16(af[mt], bg, accg[mt][nt], 0, 0, 0);
        accu[mt][nt] = __builtin_amdgcn_mfma_f32_16x16x32_bf16(af[mt], bu, accu[mt][nt], 0, 0, 0);
      }
    }
  };

  STG(0, 0);
  for (int kko = 0; kko < 23; ++kko) {
    STG((kko + 1) & 1, kko + 1);
    asm volatile("s_waitcnt vmcnt(6)" ::: "memory");  // prev tile landed; 6 new stay in flight
    __builtin_amdgcn_s_barrier();
    asm volatile("" ::: "memory");
    CMP(kko & 1);
    asm volatile("s_waitcnt lgkmcnt(0)" ::: "memory");
    __builtin_amdgcn_s_barrier();
    asm volatile("" ::: "memory");
  }
  asm volatile("s_waitcnt vmcnt(0)" ::: "memory");
  __builtin_amdgcn_s_barrier();
  asm volatile("" ::: "memory");
  CMP(1);  // kko = 23

#pragma unroll
  for (int mt = 0; mt < 4; ++mt)
#pragma unroll
    for (int r = 0; r < 4; ++r) {
      int lrow = wr * 64 + mt * 16 + q * 4 + r;
      if (lrow < rows_t) {
        size_t rowbase = (size_t)(off_e + r0 + lrow) * DFF + f0 + wc * 64;
#pragma unroll
        for (int nt = 0; nt < 4; ++nt) {
          float g = accg[mt][nt][r], u = accu[mt][nt][r];
          float h = g / (1.f + __expf(-g)) * u;
          H[rowbase + nt * 16 + lm] = f2b(h);
        }
      }
    }
}

// ---------------- stage 2: H @ WdB -> atomicAdd into out (combine fused) --------
// tile 64x128, BK=64, double-buffered + counted vmcnt, swizzled granules.
__global__ __launch_bounds__(256, 3) void k_stage2b(
    const u16* __restrict__ H, const u16* __restrict__ WdB,
    const int* __restrict__ meta, const int* __restrict__ tok,
    const float* __restrict__ wrow, float* __restrict__ out) {
  __shared__ u16 As[2][4096];
  __shared__ u16 Ws[2][8192];
  int bid = blockIdx.x;
  int wid = (bid & 7) * G2_PERX + (bid >> 3);
  int e = 0, base = 0, off_e = 0, rows_e = 0;
#pragma unroll 1
  for (e = 0; e < NEXP; ++e) {
    off_e = meta[M_OFF + e];
    rows_e = meta[M_OFF + e + 1] - off_e;
    int Tr = (rows_e + 63) >> 6;
    int c = Tr * 6;
    if (wid < base + c) break;
    base += c;
  }
  if (e == NEXP) return;
  int local = wid - base;
  int rb = (int)(((unsigned)local * 43691u) >> 18);   // local / 6
  int nb = local - rb * 6;
  int r0 = rb * 64;
  int rows_t = rows_e - r0; if (rows_t > 64) rows_t = 64;
  int n0 = nb * 128;
  int tid = threadIdx.x, lane = tid & 63, w = tid >> 6;
  int q = lane >> 4, lm = lane & 15;

  int rsub = lane >> 2;
  int g4 = (lane & 3) ^ ((lane >> 3) & 3);
  int rA = w * 16 + rsub;
  int cA = (rA < rows_t) ? rA : (rows_t - 1);
  const u16* aG = H + (size_t)(off_e + r0 + cA) * DFF + g4 * 8;
  size_t cb = (size_t)((e * 6 + nb) * 64) * 4096 + w * 1024 + rsub * 32 + g4 * 8;
  const u16* wG = WdB + cb;

  int qx = (q ^ ((lm >> 1) & 3)) * 8;
  int aoff = lm * 32 + qx;
  int boff = (w * 32 + lm) * 32 + qx;

  f32x4 acc[4][2];
#pragma unroll
  for (int i = 0; i < 4; ++i)
#pragma unroll
    for (int j = 0; j < 2; ++j) acc[i][j] = (f32x4){0.f, 0.f, 0.f, 0.f};

  auto STG = [&](int b, int kko) {
    int ka = kko * 64;
    size_t kb = (size_t)kko * 8192;
    gl16(aG + ka, &As[b][w * 512]);
    gl16(aG + ka + 32, &As[b][2048 + w * 512]);
    gl16(wG + kb, &Ws[b][w * 1024]);
    gl16(wG + kb + 512, &Ws[b][w * 1024 + 512]);
    gl16(wG + kb + 4096, &Ws[b][4096 + w * 1024]);
    gl16(wG + kb + 4608, &Ws[b][4096 + w * 1024 + 512]);
  };
  auto CMP = [&](int b) {
    const u16* ap = &As[b][aoff];
    const u16* bp = &Ws[b][boff];
#pragma unroll
    for (int s = 0; s < 2; ++s) {
      short8 af[4];
#pragma unroll
      for (int mt = 0; mt < 4; ++mt) af[mt] = *(const short8*)(ap + s * 2048 + mt * 512);
#pragma unroll
      for (int nt = 0; nt < 2; ++nt) {
        short8 bb = *(const short8*)(bp + s * 4096 + nt * 512);
#pragma unroll
        for (int mt = 0; mt < 4; ++mt)
          acc[mt][nt] = __builtin_amdgcn_mfma_f32_16x16x32_bf16(af[mt], bb, acc[mt][nt], 0, 0, 0);
      }
    }
  };

  STG(0, 0);
  for (int kko = 0; kko < 31; ++kko) {
    STG((kko + 1) & 1, kko + 1);
    asm volatile("s_waitcnt vmcnt(6)" ::: "memory");
    __builtin_amdgcn_s_barrier();
    asm volatile("" ::: "memory");
    CMP(kko & 1);
    asm volatile("s_waitcnt lgkmcnt(0)" ::: "memory");
    __builtin_amdgcn_s_barrier();
    asm volatile("" ::: "memory");
  }
  asm volatile("s_waitcnt vmcnt(0)" ::: "memory");
  __builtin_amdgcn_s_barrier();
  asm volatile("" ::: "memory");
  CMP(1);  // kko = 31

#pragma unroll
  for (int mt = 0; mt < 4; ++mt)
#pragma unroll
    for (int r = 0; r < 4; ++r) {
      int lrow = mt * 16 + q * 4 + r;
      if (lrow < rows_t) {
        int row = off_e + r0 + lrow;
        int token = tok[row];
        float wgt = wrow[row];
        float* ob = out + (size_t)token * DMODEL + n0 + w * 32;
#pragma unroll
        for (int nt = 0; nt < 2; ++nt)
          atomicAdd(&ob[nt * 16 + lm], wgt * acc[mt][nt][r]);
      }
    }
}

// ---------------- combine (fallback path only) ----------------
__global__ __launch_bounds__(192) void k_combine(
    const float* __restrict__ Op, const int* __restrict__ slot_of,
    const float* __restrict__ t2w, float* __restrict__ out) {
  int t = blockIdx.x;
  int d4 = threadIdx.x << 2;
  int s0 = slot_of[2 * t], s1 = slot_of[2 * t + 1];
  float w0 = t2w[2 * t], w1 = t2w[2 * t + 1];
  float4 a = *(const float4*)&Op[(size_t)s0 * DMODEL + d4];
  float4 b = *(const float4*)&Op[(size_t)s1 * DMODEL + d4];
  float4 r;
  r.x = w0 * a.x + w1 * b.x;
  r.y = w0 * a.y + w1 * b.y;
  r.z = w0 * a.z + w1 * b.z;
  r.w = w0 * a.w + w1 * b.w;
  *(float4*)&out[(size_t)t * DMODEL + d4] = r;
}

// ---------------- router (fallback path only; no atomics) ----------------
__global__ __launch_bounds__(256) void k_router_fb(
    const float* __restrict__ x, const float* __restrict__ gw,
    int* __restrict__ t2e, float* __restrict__ t2w, u16* __restrict__ xb) {
  int lane = threadIdx.x & 63;
  int t = blockIdx.x * 4 + (threadIdx.x >> 6);
  const float* xr = x + (size_t)t * DMODEL;
  u16* xbr = xb + (size_t)t * DMODEL;
  float acc[8];
#pragma unroll
  for (int e = 0; e < 8; ++e) acc[e] = 0.f;
#pragma unroll
  for (int i = 0; i < 12; ++i) {
    int d = lane + (i << 6);
    float xd = xr[d];
    xbr[d] = f2b(xd);
    float4 g0 = *(const float4*)(gw + d * 8);
    float4 g1 = *(const float4*)(gw + d * 8 + 4);
    acc[0] += xd * g0.x; acc[1] += xd * g0.y;
    acc[2] += xd * g0.z; acc[3] += xd * g0.w;
    acc[4] += xd * g1.x; acc[5] += xd * g1.y;
    acc[6] += xd * g1.z; acc[7] += xd * g1.w;
  }
#pragma unroll
  for (int s = 32; s >= 1; s >>= 1) {
#pragma unroll
    for (int e = 0; e < 8; ++e) acc[e] += __shfl_xor(acc[e], s);
  }
  if (lane == 0) {
    int i0 = 0;
#pragma unroll
    for (int e = 1; e < 8; ++e) if (acc[e] > acc[i0]) i0 = e;
    int i1 = (i0 == 0) ? 1 : 0;
#pragma unroll
    for (int e = 0; e < 8; ++e) if (e != i0 && acc[e] > acc[i1]) i1 = e;
    float w0 = 1.f / (1.f + __expf(acc[i1] - acc[i0]));
    t2e[2 * t] = i0; t2e[2 * t + 1] = i1;
    t2w[2 * t] = w0; t2w[2 * t + 1] = 1.f - w0;
  }
}

// ================= fallback (fp32 direct) =================
__device__ __forceinline__ void wpack(u32* lds, int k2, int n8, uint4 a, uint4 b) {
  int idx = n8 * WSTR + k2;
  lds[idx + 0 * WSTR] = (a.x & 0xffffu) | (b.x << 16);
  lds[idx + 1 * WSTR] = (a.x >> 16) | (b.x & 0xffff0000u);
  lds[idx + 2 * WSTR] = (a.y & 0xffffu) | (b.y << 16);
  lds[idx + 3 * WSTR] = (a.y >> 16) | (b.y & 0xffff0000u);
  lds[idx + 4 * WSTR] = (a.z & 0xffffu) | (b.z << 16);
  lds[idx + 5 * WSTR] = (a.z >> 16) | (b.z & 0xffff0000u);
  lds[idx + 6 * WSTR] = (a.w & 0xffffu) | (b.w << 16);
  lds[idx + 7 * WSTR] = (a.w >> 16) | (b.w & 0xffff0000u);
}

__global__ __launch_bounds__(256) void k_stage1f(
    const float* __restrict__ xv, const float* __restrict__ wgv, const float* __restrict__ wuv,
    const int* __restrict__ meta, const int* __restrict__ tok, u16* __restrict__ H) {
  __shared__ u16 Xs[64 * 32];
  __shared__ u16 Wgs[128 * BKP];
  __shared__ u16 Wus[128 * BKP];
  int e = blockIdx.z;
  int off_e = meta[M_OFF + e];
  int rows_e = meta[M_OFF + e + 1] - off_e;
  int r0 = blockIdx.y * 64;
  if (r0 >= rows_e) return;
  int rows_t = rows_e - r0; if (rows_t > 64) rows_t = 64;
  int f0 = blockIdx.x * 128;
  int tid = threadIdx.x, lane = tid & 63, w = tid >> 6;
  int wr = w >> 1, wc = w & 1;
  int srow = (w << 4) + (lane >> 2);
  int trow = (srow < rows_t) ? tok[off_e + r0 + srow] : tok[off_e];
  int xcol = (lane & 3) << 3;
  u16* xl = &Xs[srow * 32 + xcol];
  int k2 = tid >> 4, n8 = (tid & 15) << 3;
  size_t wbase = (size_t)e * (DMODEL * DFF) + (size_t)(k2 << 1) * DFF + f0 + n8;
  f32x4 accg[2][4], accu[2][4];
#pragma unroll
  for (int i = 0; i < 2; ++i)
#pragma unroll
    for (int j = 0; j < 4; ++j) {
      accg[i][j] = (f32x4){0.f, 0.f, 0.f, 0.f};
      accu[i][j] = (f32x4){0.f, 0.f, 0.f, 0.f};
    }
  for (int kk = 0; kk < DMODEL / 32; ++kk) {
    int k0 = kk << 5;
    const float* xg = xv + (size_t)trow * DMODEL + xcol;
    const float* wgp = wgv + wbase;
    const float* wup = wuv + wbase;
    uint4 xa = cvt8(*(const float4*)(xg + k0), *(const float4*)(xg + k0 + 4));
    uint4 ga = cvt8(*(const float4*)(wgp + (size_t)k0 * DFF), *(const float4*)(wgp + (size_t)k0 * DFF + 4));
    uint4 gb = cvt8(*(const float4*)(wgp + (size_t)k0 * DFF + DFF), *(const float4*)(wgp + (size_t)k0 * DFF + DFF + 4));
    uint4 ua = cvt8(*(const float4*)(wup + (size_t)k0 * DFF), *(const float4*)(wup + (size_t)k0 * DFF + 4));
    uint4 ub = cvt8(*(const float4*)(wup + (size_t)k0 * DFF + DFF), *(const float4*)(wup + (size_t)k0 * DFF + DFF + 4));
    __syncthreads();
    *(uint4*)xl = xa;
    wpack((u32*)Wgs, k2, n8, ga, gb);
    wpack((u32*)Wus, k2, n8, ua, ub);
    __syncthreads();
    short8 af[2];
#pragma unroll
    for (int mt = 0; mt < 2; ++mt)
      af[mt] = *(const short8*)&Xs[((wr << 5) + (mt << 4) + (lane & 15)) * 32 + ((lane >> 4) << 3)];
#pragma unroll
    for (int nt = 0; nt < 4; ++nt) {
      int col = (wc << 6) + (nt << 4) + (lane & 15);
      short8 bg = *(const short8*)&Wgs[col * BKP + ((lane >> 4) << 3)];
      short8 bu = *(const short8*)&Wus[col * BKP + ((lane >> 4) << 3)];
#pragma unroll
      for (int mt = 0; mt < 2; ++mt) {
        accg[mt][nt] = __builtin_amdgcn_mfma_f32_16x16x32_bf16(af[mt], bg, accg[mt][nt], 0, 0, 0);
        accu[mt][nt] = __builtin_amdgcn_mfma_f32_16x16x32_bf16(af[mt], bu, accu[mt][nt], 0, 0, 0);
      }
    }
  }
  int q = lane >> 4, c = lane & 15;
#pragma unroll
  for (int mt = 0; mt < 2; ++mt)
#pragma unroll
    for (int r = 0; r < 4; ++r) {
      int lrow = (wr << 5) + (mt << 4) + (q << 2) + r;
      if (lrow < rows_t) {
        size_t rowbase = (size_t)(off_e + r0 + lrow) * DFF + f0 + (wc << 6);
#pragma unroll
        for (int nt = 0; nt < 4; ++nt) {
          float g = accg[mt][nt][r], u = accu[mt][nt][r];
          float h = g / (1.f + __expf(-g)) * u;
          H[rowbase + (nt << 4) + c] = f2b(h);
        }
      }
    }
}

__global__ __launch_bounds__(256) void k_stage2f(
    const u16* __restrict__ H, const float* __restrict__ wdv,
    const int* __restrict__ meta, float* __restrict__ Op) {
  __shared__ u16 As[64 * 32];
  __shared__ u16 Ws[128 * BKP];
  int e = blockIdx.z;
  int off_e = meta[M_OFF + e];
  int rows_e = meta[M_OFF + e + 1] - off_e;
  int r0 = blockIdx.y * 64;
  if (r0 >= rows_e) return;
  int rows_t = rows_e - r0; if (rows_t > 64) rows_t = 64;
  int n0 = blockIdx.x * 128;
  int tid = threadIdx.x, lane = tid & 63, w = tid >> 6;
  int wr = w >> 1, wc = w & 1;
  int srow = (w << 4) + (lane >> 2);
  int hrow = off_e + r0 + ((srow < rows_t) ? srow : 0);
  const u16* ag = H + (size_t)hrow * DFF + ((lane & 3) << 3);
  u16* al = &As[srow * 32 + ((lane & 3) << 3)];
  int k2 = tid >> 4, n8 = (tid & 15) << 3;
  size_t wbase = (size_t)e * (DFF * DMODEL) + (size_t)(k2 << 1) * DMODEL + n0 + n8;
  f32x4 acc[2][4];
#pragma unroll
  for (int i = 0; i < 2; ++i)
#pragma unroll
    for (int j = 0; j < 4; ++j) acc[i][j] = (f32x4){0.f, 0.f, 0.f, 0.f};
  for (int kk = 0; kk < DFF / 32; ++kk) {
    int k0 = kk << 5;
    uint4 xa = *(const uint4*)(ag + k0);
    const float* wdp = wdv + wbase;
    uint4 ga = cvt8(*(const float4*)(wdp + (size_t)k0 * DMODEL), *(const float4*)(wdp + (size_t)k0 * DMODEL + 4));
    uint4 gb = cvt8(*(const float4*)(wdp + (size_t)k0 * DMODEL + DMODEL), *(const float4*)(wdp + (size_t)k0 * DMODEL + DMODEL + 4));
    __syncthreads();
    *(uint4*)al = xa;
    wpack((u32*)Ws, k2, n8, ga, gb);
    __syncthreads();
    short8 af[2];
#pragma unroll
    for (int mt = 0; mt < 2; ++mt)
      af[mt] = *(const short8*)&As[((wr << 5) + (mt << 4) + (lane & 15)) * 32 + ((lane >> 4) << 3)];
#pragma unroll
    for (int nt = 0; nt < 4; ++nt) {
      int col = (wc << 6) + (nt << 4) + (lane & 15);
      short8 b = *(const short8*)&Ws[col * BKP + ((lane >> 4) << 3)];
#pragma unroll
      for (int mt = 0; mt < 2; ++mt)
        acc[mt][nt] = __builtin_amdgcn_mfma_f32_16x16x32_bf16(af[mt], b, acc[mt][nt], 0, 0, 0);
    }
  }
  int q = lane >> 4, c = lane & 15;
#pragma unroll
  for (int mt = 0; mt < 2; ++mt)
#pragma unroll
    for (int r = 0; r < 4; ++r) {
      int lrow = (wr << 5) + (mt << 4) + (q << 2) + r;
      if (lrow < rows_t) {
        size_t rowbase = (size_t)(off_e + r0 + lrow) * DMODEL + n0 + (wc << 6);
#pragma unroll
        for (int nt = 0; nt < 4; ++nt)
          Op[rowbase + (nt << 4) + c] = acc[mt][nt][r];
      }
    }
}

extern "C" void kernel_launch(void* const* d_in, const int* in_sizes, int n_in,
                              void* d_out, int out_size, void* d_ws, size_t ws_size,
                              hipStream_t stream) {
  const float* x  = (const float*)d_in[0];
  const float* gw = (const float*)d_in[1];
  const float* wg = (const float*)d_in[2];
  const float* wu = (const float*)d_in[3];
  const float* wd = (const float*)d_in[4];
  float* out = (float*)d_out;

  char* ws = (char*)d_ws;
  int* meta = (int*)ws;
  int* t2e        = (int*)(ws + 256);
  int* slot_of    = (int*)(ws + 16640);
  int* tok_of_row = (int*)(ws + 33024);
  float* t2w      = (float*)(ws + 49408);
  u16* Xb         = (u16*)(ws + 65792);                 // [2048*768] bf16

  const size_t NEED = 108069120;  // fast-path ws footprint
  if (ws_size >= NEED) {
    u16* H         = (u16*)(ws + 3211520);            // [4096*2048] bf16
    float* w_of_row = (float*)(ws + 19988736);        // [4096] fp32 (Op area reuse)
    u16* WgB   = (u16*)(ws + 32571648);               // blocked bf16
    u16* WuB   = (u16*)(ws + 57737472);
    u16* WdB   = (u16*)(ws + 82903296);

    // 4 launches; wd-transpose rides inside the stage1 launch (overlaps gemm)
    k_prep<<<PREP_GRID, 256, 0, stream>>>(wg, wu, x, gw, WgB, WuB,
                                          t2e, t2w, Xb, out);
    k_scansc<<<1, 1024, 0, stream>>>(t2e, t2w, meta, tok_of_row, slot_of, w_of_row, out);
    k_stage1b<<<S1_GRID, 256, 0, stream>>>(Xb, WgB, WuB, meta, tok_of_row, H, wd, WdB);
    k_stage2b<<<G2_GRID, 256, 0, stream>>>(H, WdB, meta, tok_of_row, w_of_row, out);
  } else {
    u16* H    = (u16*)(ws + 65792);
    float* Op = (float*)(ws + 65792 + 16777216);
    float* w_of_row = (float*)(ws + 65792 + 16777216 + 12582912);
    k_router_fb<<<T_TOK / 4, 256, 0, stream>>>(x, gw, t2e, t2w, Xb);
    k_scansc<<<1, 1024, 0, stream>>>(t2e, t2w, meta, tok_of_row, slot_of, w_of_row, out);
    dim3 g1(DFF / 128, T_TOK / 64, NEXP);
    k_stage1f<<<g1, 256, 0, stream>>>(x, wg, wu, meta, tok_of_row, H);
    dim3 g2(DMODEL / 128, T_TOK / 64, NEXP);
    k_stage2f<<<g2, 256, 0, stream>>>(H, wd, meta, Op);
    k_combine<<<T_TOK, 192, 0, stream>>>(Op, slot_of, t2w, out);
  }
}